// Round 2
// baseline (7574.905 us; speedup 1.0000x reference)
//
// Persistent per-batch RNN for PQMatcher on gfx950.
// Design: 64 blocks (one per batch b) x 1024 threads. 128 sequential steps,
// all dependencies via __syncthreads(). All folded weight matrices live in
// per-thread registers as f16 pairs (v_dot2_f32_f16); Wuq (loop-invariant
// attention term) lives in LDS per block. Hidden state recurrence in f32.
#include <hip/hip_runtime.h>
#include <hip/hip_fp16.h>

typedef _Float16 h2_t __attribute__((ext_vector_type(2)));

__device__ __forceinline__ float dot2f(int w, int x, float acc) {
#if __has_builtin(__builtin_amdgcn_fdot2)
  return __builtin_amdgcn_fdot2(__builtin_bit_cast(h2_t, w),
                                __builtin_bit_cast(h2_t, x), acc, false);
#else
  h2_t a = __builtin_bit_cast(h2_t, w);
  h2_t b = __builtin_bit_cast(h2_t, x);
  return acc + (float)a[0] * (float)b[0] + (float)a[1] * (float)b[1];
#endif
}

__device__ __forceinline__ float rcp_f(float x) {
#if __has_builtin(__builtin_amdgcn_rcpf)
  return __builtin_amdgcn_rcpf(x);
#else
  return 1.0f / x;
#endif
}

__device__ __forceinline__ float fast_tanh(float x) {
  // tanh(x) = 1 - 2/(1+exp2(x*2*log2(e)))
  float e = exp2f(x * 2.885390082f);
  return 1.0f - 2.0f * rcp_f(e + 1.0f);
}
__device__ __forceinline__ float fast_sigmoid(float x) {
  return rcp_f(1.0f + exp2f(x * -1.442695041f));
}
__device__ __forceinline__ int packh2(float a, float b) {
  h2_t h;
  h[0] = (_Float16)a;
  h[1] = (_Float16)b;
  return __builtin_bit_cast(int, h);
}

#define DOT4(W, O, X, A)                                                       \
  {                                                                            \
    A = dot2f(W[(O) + 0], (X).x, A);                                           \
    A = dot2f(W[(O) + 1], (X).y, A);                                           \
    A = dot2f(W[(O) + 2], (X).z, A);                                           \
    A = dot2f(W[(O) + 3], (X).w, A);                                           \
  }

// ---------------------------------------------------------------------------
// Prep 1: fold + convert weight matrices to f16 register layouts.
//  Ma  [150 rows][304 halves]: row h = [Wp_eff(150)+pad2 | Wv row(150)+pad2]
//  Wg  [600 rows][304 halves]: folded (u-part 150 +pad2 | c-part 150 +pad2)
//  Wih [900 half-slots][304 halves]: slot s = W_ih[s>>1][(s&1)*300 .. +300)+pad4
//  Whh [452 rows][152 halves]: row r = W_hh[r][0..150)+pad2 (2 zero pad rows)
// ---------------------------------------------------------------------------
__global__ void prep_weights(const float* __restrict__ Wp,
                             const float* __restrict__ Wv,
                             const float* __restrict__ Wg,
                             const float* __restrict__ Wih,
                             const float* __restrict__ Whh,
                             __half* __restrict__ oMa, __half* __restrict__ oWg,
                             __half* __restrict__ oWih,
                             __half* __restrict__ oWhh) {
  int idx = blockIdx.x * 256 + threadIdx.x;
  const int NMa = 150 * 304, NWg = 600 * 304, NWih = 900 * 304,
            NWhh = 452 * 152;
  if (idx < NMa) {
    int h = idx / 304, c = idx % 304;
    float v = 0.f;
    if (c < 150)
      v = Wp[h * 300 + c] + Wp[h * 300 + 150 + c];
    else if (c >= 152 && c < 302)
      v = Wv[h * 150 + (c - 152)];
    oMa[idx] = __float2half(v);
    return;
  }
  idx -= NMa;
  if (idx < NWg) {
    int j = idx / 304, c = idx % 304;
    float v = 0.f;
    if (c < 150)
      v = Wg[j * 600 + c] + Wg[j * 600 + 150 + c];
    else if (c >= 152 && c < 302) {
      int d = c - 152;
      v = Wg[j * 600 + 300 + d] + Wg[j * 600 + 450 + d];
    }
    oWg[idx] = __float2half(v);
    return;
  }
  idx -= NWg;
  if (idx < NWih) {
    int s = idx / 304, c = idx % 304;
    int r = s >> 1, off = (s & 1) * 300;
    float v = (c < 300) ? Wih[r * 600 + off + c] : 0.f;
    oWih[idx] = __float2half(v);
    return;
  }
  idx -= NWih;
  if (idx < NWhh) {
    int r = idx / 152, c = idx % 152;
    float v = (r < 450 && c < 150) ? Whh[r * 150 + c] : 0.f;
    oWhh[idx] = __float2half(v);
  }
}

// ---------------------------------------------------------------------------
// Prep 2: Wuq[b][l][h] = sum_d (Wq[h,d]+Wq[h,d+150]) * Uq[l,b,d]  (f16 out)
//         Uqh[b][l][d] = (f16)Uq[l,b,d]   (b-major transpose for phase C)
// One block per l (128 blocks). Row stride padded to 152 halves.
// ---------------------------------------------------------------------------
__global__ __launch_bounds__(256) void prep_wuq(const float* __restrict__ Uq,
                                                const float* __restrict__ Wq,
                                                __half* __restrict__ oWuq,
                                                __half* __restrict__ oUqh) {
  __shared__ float sUql[64 * 150];
  const int l = blockIdx.x, tid = threadIdx.x;
  for (int idx = tid; idx < 9600; idx += 256) sUql[idx] = Uq[l * 9600 + idx];
  __syncthreads();
  for (int idx = tid; idx < 64 * 152; idx += 256) {
    int bb = idx / 152, d = idx % 152;
    float v = (d < 150) ? sUql[bb * 150 + d] : 0.f;
    oUqh[(size_t)bb * 19456 + l * 152 + d] = __float2half(v);
  }
  if (tid < 152) {
    const int h = tid;
    if (h < 150) {
      float wq[150];
#pragma unroll
      for (int d = 0; d < 150; ++d)
        wq[d] = Wq[h * 300 + d] + Wq[h * 300 + 150 + d];
      for (int bb = 0; bb < 64; ++bb) {
        float acc = 0.f;
#pragma unroll
        for (int d = 0; d < 150; ++d) acc += wq[d] * sUql[bb * 150 + d];
        oWuq[(size_t)bb * 19456 + l * 152 + h] = __float2half(acc);
      }
    } else {
      for (int bb = 0; bb < 64; ++bb)
        oWuq[(size_t)bb * 19456 + l * 152 + h] = __float2half(0.f);
    }
  }
}

// ---------------------------------------------------------------------------
// Main persistent kernel. One block per batch element.
// Weight register ownership (w0[152], w1[152] ints = f16 pairs):
//  t in [0,150)   : w0 = Ma row t            ; w1 = Wih slot t
//  t in [150,750) : w0 = Wg row (t-150)      ; w1 = Wih slot t
//  t in [750,900) : w0 = Wih slot t          ; w1 = Whh row (t-750)
//  t in [900,1024): w0 = Whh rows 150+2m,+1  ; w1 = Whh row 398+m (m<52)
// ---------------------------------------------------------------------------
__global__ __launch_bounds__(1024, 1) void pq_main(
    const float* __restrict__ Up, const float* __restrict__ V,
    const float* __restrict__ v0, const float* __restrict__ b_ih,
    const float* __restrict__ b_hh, const int* __restrict__ gWuq,
    const __half* __restrict__ gUqh, const int* __restrict__ gMa,
    const int* __restrict__ gWg, const int* __restrict__ gWih,
    const int* __restrict__ gWhh, float* __restrict__ out) {
  __shared__ __align__(16) int sWuq[128 * 76];  // f16 pairs [l][76 words]
  __shared__ __align__(16) float sTV[304];      // float4[76]: {tp0,tp1,V0,V1}
  __shared__ __align__(16) float sV[152];
  __shared__ __align__(16) float sGh[456];
  __shared__ __align__(16) float sS[128];
  __shared__ __align__(16) float sC0[152];
  __shared__ __align__(16) float sCp[608];
  __shared__ __align__(16) float sU[152];
  __shared__ __align__(16) float sv_[152];
  __shared__ __align__(16) int sXd[152];  // h2: [u(76w) | c0(76w)]
  __shared__ __align__(16) int svh[76];   // h2 of hidden v
  __shared__ __align__(16) int sRgh[304]; // h2: [rg 0..299 pad4 | rg 300..599 pad4]
  __shared__ __align__(16) float sGi[456];
  __shared__ __align__(16) float sBih[456];
  __shared__ __align__(16) float sBhh[456];

  const int t = threadIdx.x;
  const int b = blockIdx.x;

  // ---- load weight registers ----
  int w0[152], w1[152];
  {
    const int* p0;
    const int* p1;
    if (t < 150)
      p0 = gMa + t * 152;
    else if (t < 750)
      p0 = gWg + (t - 150) * 152;
    else if (t < 900)
      p0 = gWih + t * 152;
    else
      p0 = gWhh + (150 + 2 * (t - 900)) * 76;
    if (t < 750)
      p1 = gWih + t * 152;
    else if (t < 900)
      p1 = gWhh + (t - 750) * 76;
    else if (t < 952)
      p1 = gWhh + (398 + (t - 900)) * 76;
    else
      p1 = gWhh;  // dummy (never used)
#pragma unroll
    for (int k = 0; k < 38; ++k) {
      int4 a = ((const int4*)p0)[k];
      w0[4 * k + 0] = a.x;
      w0[4 * k + 1] = a.y;
      w0[4 * k + 2] = a.z;
      w0[4 * k + 3] = a.w;
      int4 c = ((const int4*)p1)[k];
      w1[4 * k + 0] = c.x;
      w1[4 * k + 1] = c.y;
      w1[4 * k + 2] = c.z;
      w1[4 * k + 3] = c.w;
    }
  }

  // ---- LDS init ----
  for (int idx = t; idx < 9728; idx += 1024) sWuq[idx] = gWuq[b * 9728 + idx];
  if (t < 150) {
    sV[t] = V[b * 150 + t];
    float v_ = v0[b * 150 + t];
    sv_[t] = v_;
    float vn = __shfl_down(v_, 1);
    if (!(t & 1)) svh[t >> 1] = packh2(v_, vn);
    float u_ = Up[b * 150 + t];  // step 0
    sU[t] = u_;
    float un = __shfl_down(u_, 1);
    if (!(t & 1)) sXd[t >> 1] = packh2(u_, un);
  }
  for (int idx = t; idx < 450; idx += 1024) {
    sBih[idx] = b_ih[idx];
    sBhh[idx] = b_hh[idx];
  }
  if (t == 0) {  // zero padding words (avoid NaN*0 from poisoned LDS)
    svh[75] = 0;
    sXd[75] = 0;
    sXd[151] = 0;
    sRgh[150] = 0;
    sRgh[151] = 0;
    sRgh[302] = 0;
    sRgh[303] = 0;
  }
  const int c_lq = t / 150;  // phase C constants (valid for t<600)
  const int c_d0 = t - c_lq * 150;
  __syncthreads();

#pragma unroll 1
  for (int i = 0; i < 128; ++i) {
    // prefetch next step's Up slice (consumed in phase F)
    float unext = 0.f;
    if (t >= 256 && t < 406) {
      int ii = (i < 127) ? (i + 1) : 127;
      unext = Up[ii * 9600 + b * 150 + (t - 256)];
    }

    // ---- Phase A: tpre = Wp_eff*u + Wv*v  (t<150); gh = Whh*v + b_hh (t>=750)
    if (t < 150) {
      float acc = 0.f;
#pragma unroll
      for (int k = 0; k < 19; ++k) {
        int4 x = ((const int4*)sXd)[k];
        DOT4(w0, 4 * k, x, acc)
      }
#pragma unroll
      for (int k = 0; k < 19; ++k) {
        int4 x = ((const int4*)svh)[k];
        DOT4(w0, 76 + 4 * k, x, acc)
      }
      float tn = __shfl_down(acc, 1);
      if (!(t & 1)) {
        float4 tv;
        tv.x = acc;
        tv.y = tn;
        tv.z = sV[t];
        tv.w = sV[t + 1];
        ((float4*)sTV)[t >> 1] = tv;
      }
    } else if (t >= 750) {
      if (t < 900) {
        int r = t - 750;
        float acc = 0.f;
#pragma unroll
        for (int k = 0; k < 19; ++k) {
          int4 x = ((const int4*)svh)[k];
          DOT4(w1, 4 * k, x, acc)
        }
        sGh[r] = acc + sBhh[r];
      } else {
        int m = t - 900;
        int r0 = 150 + 2 * m;
        float a0 = 0.f, a1 = 0.f;
#pragma unroll
        for (int k = 0; k < 19; ++k) {
          int4 x = ((const int4*)svh)[k];
          DOT4(w0, 4 * k, x, a0)
          DOT4(w0, 76 + 4 * k, x, a1)
        }
        sGh[r0] = a0 + sBhh[r0];
        sGh[r0 + 1] = a1 + sBhh[r0 + 1];
        if (t < 952) {
          int r2 = 398 + m;
          float a2 = 0.f;
#pragma unroll
          for (int k = 0; k < 19; ++k) {
            int4 x = ((const int4*)svh)[k];
            DOT4(w1, 4 * k, x, a2)
          }
          sGh[r2] = a2 + sBhh[r2];
        }
      }
    }
    __syncthreads();

    // ---- Phase B: s[l] = sum_h tanh(tpre[h]+Wuq[l,h]) * V[h]
    {
      const int l = t >> 3, sub = t & 7;
      const int base = l * 76;
      const int niter = (sub < 3) ? 10 : 9;
      float acc = 0.f;
#pragma unroll
      for (int k = 0; k < 10; ++k) {
        if (k < niter) {
          int w = sub + 8 * k;
          int q = sWuq[base + w];
          float4 tv = ((const float4*)sTV)[w];
          h2_t hq = __builtin_bit_cast(h2_t, q);
          float a0 = (float)hq[0] + tv.x;
          float a1 = (float)hq[1] + tv.y;
          acc += fast_tanh(a0) * tv.z;
          acc += fast_tanh(a1) * tv.w;
        }
      }
      acc += __shfl_xor(acc, 1);
      acc += __shfl_xor(acc, 2);
      acc += __shfl_xor(acc, 4);
      if (sub == 0) sS[l] = acc;
    }
    __syncthreads();

    // ---- Softmax over l (single wave)
    if (t < 64) {
      float s0 = sS[t], s1 = sS[t + 64];
      float m = fmaxf(s0, s1);
#pragma unroll
      for (int o = 1; o < 64; o <<= 1) m = fmaxf(m, __shfl_xor(m, o));
      float e0 = exp2f((s0 - m) * 1.442695041f);
      float e1 = exp2f((s1 - m) * 1.442695041f);
      float sum = e0 + e1;
#pragma unroll
      for (int o = 1; o < 64; o <<= 1) sum += __shfl_xor(sum, o);
      float inv = rcp_f(sum);
      sS[t] = e0 * inv;
      sS[t + 64] = e1 * inv;
    }
    __syncthreads();

    // ---- Phase C: c0 partials (t<600): 4 l-chunks x 150 d0
    if (t < 600) {
      const __half* src = gUqh + (size_t)b * 19456 + c_lq * 32 * 152 + c_d0;
      float acc = 0.f;
#pragma unroll
      for (int j = 0; j < 32; ++j) {
        float a = sS[c_lq * 32 + j];
        acc += a * __half2float(src[j * 152]);
      }
      sCp[c_lq * 152 + c_d0] = acc;
    }
    __syncthreads();

    // ---- Phase CS: c0 = sum of 4 partials; pack into sXd c-part
    if (t < 150) {
      float c0 = sCp[t] + sCp[152 + t] + sCp[304 + t] + sCp[456 + t];
      sC0[t] = c0;
      float cn = __shfl_down(c0, 1);
      if (!(t & 1)) sXd[76 + (t >> 1)] = packh2(c0, cn);
    }
    __syncthreads();

    // ---- Phase D: y = Wg_eff * [u;c0]; rg = sigmoid(y)*r; write f16 rg
    if (t >= 150 && t < 750) {
      int j = t - 150;
      float acc = 0.f;
#pragma unroll
      for (int k = 0; k < 38; ++k) {
        int4 x = ((const int4*)sXd)[k];
        DOT4(w0, 4 * k, x, acc)
      }
      float rb;
      if (j < 150)
        rb = sU[j];
      else if (j < 300)
        rb = sU[j - 150];
      else if (j < 450)
        rb = sC0[j - 300];
      else
        rb = sC0[j - 450];
      float rg = rb * fast_sigmoid(acc);
      int idx = (j < 300) ? j : (j + 4);
      ((__half*)sRgh)[idx] = __float2half(rg);
    }
    __syncthreads();

    // ---- Phase E: gi = W_ih * rg + b_ih (half-rows, pair-reduce via shfl)
    // Each half-row dots 304 halves (300 + aligned zero pads) = 38 int4.
    if (t < 900) {
      const int hf = t & 1, r = t >> 1;
      float acc = 0.f;
      if (t < 750) {
#pragma unroll
        for (int k = 0; k < 38; ++k) {
          int4 x = ((const int4*)sRgh)[hf * 38 + k];
          DOT4(w1, 4 * k, x, acc)
        }
      } else {
#pragma unroll
        for (int k = 0; k < 38; ++k) {
          int4 x = ((const int4*)sRgh)[hf * 38 + k];
          DOT4(w0, 4 * k, x, acc)
        }
      }
      float other = __shfl_xor(acc, 1);
      if (!hf) sGi[r] = acc + other + sBih[r];
    }
    __syncthreads();

    // ---- Phase F: GRU update + output store; loaders stage next u
    if (t < 150) {
      float ir = sGi[t], iz = sGi[150 + t], in_ = sGi[300 + t];
      float hr = sGh[t], hz = sGh[150 + t], hn = sGh[300 + t];
      float rr = fast_sigmoid(ir + hr);
      float zz = fast_sigmoid(iz + hz);
      float nn = fast_tanh(in_ + rr * hn);
      float vold = sv_[t];
      float hv = nn + zz * (vold - nn);
      out[i * 9600 + b * 150 + t] = hv;
      sv_[t] = hv;
      float hv1 = __shfl_down(hv, 1);
      if (!(t & 1)) svh[t >> 1] = packh2(hv, hv1);
    } else if (t >= 256 && t < 406) {
      int t2 = t - 256;
      sU[t2] = unext;
      float un = __shfl_down(unext, 1);
      if (!(t2 & 1)) sXd[t2 >> 1] = packh2(unext, un);
    }
    __syncthreads();
  }
}

// ---------------------------------------------------------------------------
extern "C" void kernel_launch(void* const* d_in, const int* in_sizes, int n_in,
                              void* d_out, int out_size, void* d_ws,
                              size_t ws_size, hipStream_t stream) {
  const float* Up = (const float*)d_in[0];
  const float* Uq = (const float*)d_in[1];
  const float* Wp = (const float*)d_in[2];
  const float* Wq = (const float*)d_in[3];
  const float* Wv = (const float*)d_in[4];
  const float* Wg = (const float*)d_in[5];
  const float* V = (const float*)d_in[6];
  const float* v0 = (const float*)d_in[7];
  const float* Wih = (const float*)d_in[8];
  const float* Whh = (const float*)d_in[9];
  const float* bih = (const float*)d_in[10];
  const float* bhh = (const float*)d_in[11];

  char* ws = (char*)d_ws;
  __half* wsWuq = (__half*)(ws);                 // 2,490,368 B
  __half* wsUqh = (__half*)(ws + 2490368);       // 2,490,368 B
  __half* wsMa = (__half*)(ws + 4980736);        //    91,200 B
  __half* wsWg = (__half*)(ws + 5071936);        //   364,800 B
  __half* wsWih = (__half*)(ws + 5436736);       //   547,200 B
  __half* wsWhh = (__half*)(ws + 5983936);       //   137,408 B  (end 6,121,344)

  prep_weights<<<2228, 256, 0, stream>>>(Wp, Wv, Wg, Wih, Whh, wsMa, wsWg,
                                         wsWih, wsWhh);
  prep_wuq<<<128, 256, 0, stream>>>(Uq, Wq, wsWuq, wsUqh);
  pq_main<<<64, 1024, 0, stream>>>(Up, V, v0, bih, bhh, (const int*)wsWuq,
                                   wsUqh, (const int*)wsMa, (const int*)wsWg,
                                   (const int*)wsWih, (const int*)wsWhh,
                                   (float*)d_out);
}

// Round 3
// 6200.957 us; speedup vs baseline: 1.2216x; 1.2216x over previous
//
// Persistent per-batch RNN for PQMatcher on gfx950.
// 64 blocks (one per batch) x 1024 threads, 128 sequential steps.
// Weights are f16, folded, stored CHUNK-TRANSPOSED [chunk][row] and split in
// three storage classes per row: register prefix (named int4 a0..a9,b0..b9,
// <=80 words/thread under the 128-VGPR cap at 16 waves/CU), LDS middle
// (~98 KB dynamic LDS), streamed tail (read from L2 every step, coalesced).
#include <hip/hip_runtime.h>
#include <hip/hip_fp16.h>

typedef _Float16 h2_t __attribute__((ext_vector_type(2)));

__device__ __forceinline__ float dot2f(int w, int x, float acc) {
#if __has_builtin(__builtin_amdgcn_fdot2)
  return __builtin_amdgcn_fdot2(__builtin_bit_cast(h2_t, w),
                                __builtin_bit_cast(h2_t, x), acc, false);
#else
  h2_t a = __builtin_bit_cast(h2_t, w);
  h2_t b = __builtin_bit_cast(h2_t, x);
  return acc + (float)a[0] * (float)b[0] + (float)a[1] * (float)b[1];
#endif
}

__device__ __forceinline__ float rcp_f(float x) {
#if __has_builtin(__builtin_amdgcn_rcpf)
  return __builtin_amdgcn_rcpf(x);
#else
  return 1.0f / x;
#endif
}

__device__ __forceinline__ float fast_tanh(float x) {
  float e = exp2f(x * 2.885390082f);
  return 1.0f - 2.0f * rcp_f(e + 1.0f);
}
__device__ __forceinline__ float fast_sigmoid(float x) {
  return rcp_f(1.0f + exp2f(x * -1.442695041f));
}
__device__ __forceinline__ int packh2(float a, float b) {
  h2_t h;
  h[0] = (_Float16)a;
  h[1] = (_Float16)b;
  return __builtin_bit_cast(int, h);
}

#define DOTC(W, X, A)                                                          \
  {                                                                            \
    int4 _x = (X);                                                             \
    A = dot2f((W).x, _x.x, A);                                                 \
    A = dot2f((W).y, _x.y, A);                                                 \
    A = dot2f((W).z, _x.z, A);                                                 \
    A = dot2f((W).w, _x.w, A);                                                 \
  }

// Chunk-transposed geometry (int4 chunks of 4 words = 8 halves per row):
//  Ma : NR=150, 38 chunks: reg 0-9, lds 10-16, stream 17-37
//  Wg : NR=600, 38 chunks: reg 0-9, lds 10-13, stream 14-37
//  Wih: NR=900, 38 chunks: reg 0-9, lds 10-11, stream 12-37
//  Whh: NR=452, 19 chunks: reg 0-4, lds 5-6,  stream 7-18
// ---------------------------------------------------------------------------
__global__ void prep_weights(const float* __restrict__ Wp,
                             const float* __restrict__ Wv,
                             const float* __restrict__ Wg,
                             const float* __restrict__ Wih,
                             const float* __restrict__ Whh,
                             __half* __restrict__ oMa, __half* __restrict__ oWg,
                             __half* __restrict__ oWih,
                             __half* __restrict__ oWhh) {
  int idx = blockIdx.x * 256 + threadIdx.x;
  const int NMa = 150 * 304, NWg = 600 * 304, NWih = 900 * 304,
            NWhh = 452 * 152;
  if (idx < NMa) {
    int r = idx / 304, c = idx % 304;
    float v = 0.f;
    if (c < 150)
      v = Wp[r * 300 + c] + Wp[r * 300 + 150 + c];
    else if (c >= 152 && c < 302)
      v = Wv[r * 150 + (c - 152)];
    oMa[(c >> 3) * 1200 + r * 8 + (c & 7)] = __float2half(v);
    return;
  }
  idx -= NMa;
  if (idx < NWg) {
    int r = idx / 304, c = idx % 304;
    float v = 0.f;
    if (c < 150)
      v = Wg[r * 600 + c] + Wg[r * 600 + 150 + c];
    else if (c >= 152 && c < 302) {
      int d = c - 152;
      v = Wg[r * 600 + 300 + d] + Wg[r * 600 + 450 + d];
    }
    oWg[(c >> 3) * 4800 + r * 8 + (c & 7)] = __float2half(v);
    return;
  }
  idx -= NWg;
  if (idx < NWih) {
    int s = idx / 304, c = idx % 304;
    int r = s >> 1, off = (s & 1) * 300;
    float v = (c < 300) ? Wih[r * 600 + off + c] : 0.f;
    oWih[(c >> 3) * 7200 + s * 8 + (c & 7)] = __float2half(v);
    return;
  }
  idx -= NWih;
  if (idx < NWhh) {
    int r = idx / 152, c = idx % 152;
    float v = (r < 450 && c < 150) ? Whh[r * 150 + c] : 0.f;
    oWhh[(c >> 3) * 3616 + r * 8 + (c & 7)] = __float2half(v);
  }
}

// ---------------------------------------------------------------------------
// Prep 2: Wuq[b][l][h] = sum_d (Wq[h,d]+Wq[h,d+150]) * Uq[l,b,d]  (f16 out)
//         Uqh[b][l][d] = (f16)Uq[l,b,d]
// ---------------------------------------------------------------------------
__global__ __launch_bounds__(256) void prep_wuq(const float* __restrict__ Uq,
                                                const float* __restrict__ Wq,
                                                __half* __restrict__ oWuq,
                                                __half* __restrict__ oUqh) {
  __shared__ float sUql[64 * 150];
  const int l = blockIdx.x, tid = threadIdx.x;
  for (int idx = tid; idx < 9600; idx += 256) sUql[idx] = Uq[l * 9600 + idx];
  __syncthreads();
  for (int idx = tid; idx < 64 * 152; idx += 256) {
    int bb = idx / 152, d = idx % 152;
    float v = (d < 150) ? sUql[bb * 150 + d] : 0.f;
    oUqh[(size_t)bb * 19456 + l * 152 + d] = __float2half(v);
  }
  if (tid < 152) {
    const int h = tid;
    if (h < 150) {
      float wq[150];
#pragma unroll
      for (int d = 0; d < 150; ++d)
        wq[d] = Wq[h * 300 + d] + Wq[h * 300 + 150 + d];
      for (int bb = 0; bb < 64; ++bb) {
        float acc = 0.f;
#pragma unroll
        for (int d = 0; d < 150; ++d) acc += wq[d] * sUql[bb * 150 + d];
        oWuq[(size_t)bb * 19456 + l * 152 + h] = __float2half(acc);
      }
    } else {
      for (int bb = 0; bb < 64; ++bb)
        oWuq[(size_t)bb * 19456 + l * 152 + h] = __float2half(0.f);
    }
  }
}

// ---------------------------------------------------------------------------
// Main persistent kernel. Register weight ownership (int4 a0..a9, b0..b9):
//  t<150      : a0-a9 = Ma row t ch0-9        ; b0-b9 = Wih slot t ch0-9
//  t in[150,750): a0-a9 = Wg row (t-150) ch0-9; b0-b9 = Wih slot t ch0-9
//  t in[750,900): a0-a4 = Whh row (t-750) ch0-4; b0-b9 = Wih slot t ch0-9
//  t>=900 (m=t-900): a0-a4 = Whh row 150+2m; a5-a9 = row 151+2m;
//                    b0-b4 = Whh row 398+m (m<52)
// ---------------------------------------------------------------------------
__global__ __launch_bounds__(1024, 1) void pq_main(
    const float* __restrict__ Up, const float* __restrict__ V,
    const float* __restrict__ v0, const float* __restrict__ b_ih,
    const float* __restrict__ b_hh, const int* __restrict__ gWuq,
    const __half* __restrict__ gUqh, const int* __restrict__ gMa,
    const int* __restrict__ gWg, const int* __restrict__ gWih,
    const int* __restrict__ gWhh, float* __restrict__ out) {
  __shared__ __align__(16) int sWuq[128 * 76];
  __shared__ __align__(16) float sTV[304];
  __shared__ __align__(16) float sV[152];
  __shared__ __align__(16) float sGh[456];
  __shared__ __align__(16) float sS[128];
  __shared__ __align__(16) float sC0[152];
  __shared__ __align__(16) float sCp[608];
  __shared__ __align__(16) float sU[152];
  __shared__ __align__(16) float sv_[152];
  __shared__ __align__(16) int sXd[152];
  __shared__ __align__(16) int svh[76];
  __shared__ __align__(16) int sRgh[304];
  __shared__ __align__(16) float sGi[456];
  __shared__ __align__(16) float sBih[456];
  __shared__ __align__(16) float sBhh[456];
  extern __shared__ __align__(16) int4 dyn4[];
  int4* lMa4 = dyn4;            // 1050 int4 (chunks 10-16 of Ma)
  int4* lWg4 = dyn4 + 1050;     // 2400 int4 (chunks 10-13 of Wg)
  int4* lWih4 = dyn4 + 3450;    // 1800 int4 (chunks 10-11 of Wih)
  int4* lWhh4 = dyn4 + 5250;    // 904 int4  (chunks 5-6 of Whh)

  const int t = threadIdx.x;
  const int b = blockIdx.x;

  const int4* MaT4 = (const int4*)gMa;
  const int4* WgT4 = (const int4*)gWg;
  const int4* WihT4 = (const int4*)gWih;
  const int4* WhhT4 = (const int4*)gWhh;
  const int4* MaS4 = MaT4 + 2550;    // chunk 17
  const int4* WgS4 = WgT4 + 8400;    // chunk 14
  const int4* WihS4 = WihT4 + 10800; // chunk 12
  const int4* WhhS4 = WhhT4 + 3164;  // chunk 7

  // ---- load register weight chunks ----
  int4 a0, a1, a2, a3, a4, a5, a6, a7, a8, a9;
  int4 b0, b1, b2, b3, b4, b5, b6, b7, b8, b9;
  {
    const int4 *p0, *p0b, *p1;
    int s0, s1;
    if (t < 150) {
      p0 = MaT4 + t; s0 = 150; p0b = p0 + 5 * 150;
    } else if (t < 750) {
      p0 = WgT4 + (t - 150); s0 = 600; p0b = p0 + 5 * 600;
    } else if (t < 900) {
      p0 = WhhT4 + (t - 750); s0 = 452; p0b = p0;
    } else {
      int m = t - 900;
      p0 = WhhT4 + (150 + 2 * m); s0 = 452; p0b = WhhT4 + (151 + 2 * m);
    }
    if (t < 900) {
      p1 = WihT4 + t; s1 = 900;
    } else {
      int m = t - 900;
      p1 = WhhT4 + ((m < 52) ? (398 + m) : 0); s1 = 452;
    }
    a0 = p0[0]; a1 = p0[s0]; a2 = p0[2 * s0]; a3 = p0[3 * s0]; a4 = p0[4 * s0];
    a5 = p0b[0]; a6 = p0b[s0]; a7 = p0b[2 * s0]; a8 = p0b[3 * s0];
    a9 = p0b[4 * s0];
    b0 = p1[0]; b1 = p1[s1]; b2 = p1[2 * s1]; b3 = p1[3 * s1]; b4 = p1[4 * s1];
    b5 = p1[5 * s1]; b6 = p1[6 * s1]; b7 = p1[7 * s1]; b8 = p1[8 * s1];
    b9 = p1[9 * s1];
  }

  // ---- stage LDS weight chunks (contiguous block copies) ----
  for (int idx = t; idx < 1050; idx += 1024) lMa4[idx] = MaT4[1500 + idx];
  for (int idx = t; idx < 2400; idx += 1024) lWg4[idx] = WgT4[6000 + idx];
  for (int idx = t; idx < 1800; idx += 1024) lWih4[idx] = WihT4[9000 + idx];
  for (int idx = t; idx < 904; idx += 1024) lWhh4[idx] = WhhT4[2260 + idx];

  // ---- LDS working-state init ----
  for (int idx = t; idx < 9728; idx += 1024) sWuq[idx] = gWuq[b * 9728 + idx];
  if (t < 150) {
    sV[t] = V[b * 150 + t];
    float v_ = v0[b * 150 + t];
    sv_[t] = v_;
    float vn = __shfl_down(v_, 1);
    if (!(t & 1)) svh[t >> 1] = packh2(v_, vn);
    float u_ = Up[b * 150 + t];
    sU[t] = u_;
    float un = __shfl_down(u_, 1);
    if (!(t & 1)) sXd[t >> 1] = packh2(u_, un);
  }
  for (int idx = t; idx < 450; idx += 1024) {
    sBih[idx] = b_ih[idx];
    sBhh[idx] = b_hh[idx];
  }
  if (t == 0) {
    svh[75] = 0;
    sXd[75] = 0;
    sXd[151] = 0;
    sRgh[150] = 0;
    sRgh[151] = 0;
    sRgh[302] = 0;
    sRgh[303] = 0;
  }
  const int4* sXd4 = (const int4*)sXd;
  const int4* svh4 = (const int4*)svh;
  const int c_lq = t / 150;
  const int c_d0 = t - c_lq * 150;
  __syncthreads();

#pragma unroll 1
  for (int i = 0; i < 128; ++i) {
    float unext = 0.f;
    if (t >= 256 && t < 406) {
      int ii = (i < 127) ? (i + 1) : 127;
      unext = Up[ii * 9600 + b * 150 + (t - 256)];
    }

    // ---- Phase A: tpre (t<150); gh = Whh*v + b_hh (t>=750)
    if (t < 150) {
      float acc = 0.f;
      DOTC(a0, sXd4[0], acc) DOTC(a1, sXd4[1], acc) DOTC(a2, sXd4[2], acc)
      DOTC(a3, sXd4[3], acc) DOTC(a4, sXd4[4], acc) DOTC(a5, sXd4[5], acc)
      DOTC(a6, sXd4[6], acc) DOTC(a7, sXd4[7], acc) DOTC(a8, sXd4[8], acc)
      DOTC(a9, sXd4[9], acc)
#pragma unroll
      for (int k = 0; k < 7; ++k) {
        int4 w = lMa4[k * 150 + t];
        DOTC(w, sXd4[10 + k], acc)
      }
      {
        const int4* sp = MaS4 + t;
        int4 f0 = sp[0], f1 = sp[150];
#pragma unroll
        for (int k = 0; k < 21; ++k) {
          int4 w = f0;
          f0 = f1;
          if (k < 19) f1 = sp[(k + 2) * 150];
          int4 x = (k < 2) ? sXd4[17 + k] : svh4[k - 2];
          DOTC(w, x, acc)
        }
      }
      float tn = __shfl_down(acc, 1);
      if (!(t & 1)) {
        float4 tv;
        tv.x = acc;
        tv.y = tn;
        tv.z = sV[t];
        tv.w = sV[t + 1];
        ((float4*)sTV)[t >> 1] = tv;
      }
    } else if (t >= 750) {
      if (t < 900) {
        int r = t - 750;
        float acc = 0.f;
        DOTC(a0, svh4[0], acc) DOTC(a1, svh4[1], acc) DOTC(a2, svh4[2], acc)
        DOTC(a3, svh4[3], acc) DOTC(a4, svh4[4], acc)
        {
          int4 w = lWhh4[r];
          DOTC(w, svh4[5], acc)
          w = lWhh4[452 + r];
          DOTC(w, svh4[6], acc)
        }
        {
          const int4* sp = WhhS4 + r;
          int4 f0 = sp[0], f1 = sp[452];
#pragma unroll
          for (int k = 0; k < 12; ++k) {
            int4 w = f0;
            f0 = f1;
            if (k < 10) f1 = sp[(k + 2) * 452];
            DOTC(w, svh4[7 + k], acc)
          }
        }
        sGh[r] = acc + sBhh[r];
      } else {
        int m = t - 900;
        int r0 = 150 + 2 * m, r1 = r0 + 1;
        float A0 = 0.f, A1 = 0.f;
        DOTC(a0, svh4[0], A0) DOTC(a1, svh4[1], A0) DOTC(a2, svh4[2], A0)
        DOTC(a3, svh4[3], A0) DOTC(a4, svh4[4], A0)
        DOTC(a5, svh4[0], A1) DOTC(a6, svh4[1], A1) DOTC(a7, svh4[2], A1)
        DOTC(a8, svh4[3], A1) DOTC(a9, svh4[4], A1)
        {
          int4 w = lWhh4[r0];
          DOTC(w, svh4[5], A0)
          w = lWhh4[452 + r0];
          DOTC(w, svh4[6], A0)
          w = lWhh4[r1];
          DOTC(w, svh4[5], A1)
          w = lWhh4[452 + r1];
          DOTC(w, svh4[6], A1)
        }
        {
          const int4* sp = WhhS4 + r0;
          int4 f0 = sp[0], g0 = sp[1], f1 = sp[452], g1 = sp[453];
#pragma unroll
          for (int k = 0; k < 12; ++k) {
            int4 w = f0, u = g0;
            f0 = f1;
            g0 = g1;
            if (k < 10) {
              f1 = sp[(k + 2) * 452];
              g1 = sp[(k + 2) * 452 + 1];
            }
            int4 x = svh4[7 + k];
            DOTC(w, x, A0)
            DOTC(u, x, A1)
          }
        }
        sGh[r0] = A0 + sBhh[r0];
        sGh[r1] = A1 + sBhh[r1];
        if (m < 52) {
          int r2 = 398 + m;
          float A2 = 0.f;
          DOTC(b0, svh4[0], A2) DOTC(b1, svh4[1], A2) DOTC(b2, svh4[2], A2)
          DOTC(b3, svh4[3], A2) DOTC(b4, svh4[4], A2)
          {
            int4 w = lWhh4[r2];
            DOTC(w, svh4[5], A2)
            w = lWhh4[452 + r2];
            DOTC(w, svh4[6], A2)
          }
          {
            const int4* sp = WhhS4 + r2;
            int4 f0 = sp[0], f1 = sp[452];
#pragma unroll
            for (int k = 0; k < 12; ++k) {
              int4 w = f0;
              f0 = f1;
              if (k < 10) f1 = sp[(k + 2) * 452];
              DOTC(w, svh4[7 + k], A2)
            }
          }
          sGh[r2] = A2 + sBhh[r2];
        }
      }
    }
    __syncthreads();

    // ---- Phase B: s[l] = sum_h tanh(tpre[h]+Wuq[l,h]) * V[h]
    {
      const int l = t >> 3, sub = t & 7;
      const int base = l * 76;
      const int niter = (sub < 3) ? 10 : 9;
      float acc = 0.f;
#pragma unroll
      for (int k = 0; k < 10; ++k) {
        if (k < niter) {
          int w = sub + 8 * k;
          int q = sWuq[base + w];
          float4 tv = ((const float4*)sTV)[w];
          h2_t hq = __builtin_bit_cast(h2_t, q);
          float x0 = (float)hq[0] + tv.x;
          float x1 = (float)hq[1] + tv.y;
          acc += fast_tanh(x0) * tv.z;
          acc += fast_tanh(x1) * tv.w;
        }
      }
      acc += __shfl_xor(acc, 1);
      acc += __shfl_xor(acc, 2);
      acc += __shfl_xor(acc, 4);
      if (sub == 0) sS[l] = acc;
    }
    __syncthreads();

    // ---- Softmax over l (single wave)
    if (t < 64) {
      float s0 = sS[t], s1 = sS[t + 64];
      float m = fmaxf(s0, s1);
#pragma unroll
      for (int o = 1; o < 64; o <<= 1) m = fmaxf(m, __shfl_xor(m, o));
      float e0 = exp2f((s0 - m) * 1.442695041f);
      float e1 = exp2f((s1 - m) * 1.442695041f);
      float sum = e0 + e1;
#pragma unroll
      for (int o = 1; o < 64; o <<= 1) sum += __shfl_xor(sum, o);
      float inv = rcp_f(sum);
      sS[t] = e0 * inv;
      sS[t + 64] = e1 * inv;
    }
    __syncthreads();

    // ---- Phase C: c0 partials (t<600)
    if (t < 600) {
      const __half* src = gUqh + (size_t)b * 19456 + c_lq * 32 * 152 + c_d0;
      float acc = 0.f;
#pragma unroll
      for (int j = 0; j < 32; ++j) {
        float a = sS[c_lq * 32 + j];
        acc += a * __half2float(src[j * 152]);
      }
      sCp[c_lq * 152 + c_d0] = acc;
    }
    __syncthreads();

    // ---- Phase CS: c0 = sum of partials
    if (t < 150) {
      float c0 = sCp[t] + sCp[152 + t] + sCp[304 + t] + sCp[456 + t];
      sC0[t] = c0;
      float cn = __shfl_down(c0, 1);
      if (!(t & 1)) sXd[76 + (t >> 1)] = packh2(c0, cn);
    }
    __syncthreads();

    // ---- Phase D: rg = sigmoid(Wg_eff*[u;c0]) * r
    if (t >= 150 && t < 750) {
      int j = t - 150;
      float acc = 0.f;
      DOTC(a0, sXd4[0], acc) DOTC(a1, sXd4[1], acc) DOTC(a2, sXd4[2], acc)
      DOTC(a3, sXd4[3], acc) DOTC(a4, sXd4[4], acc) DOTC(a5, sXd4[5], acc)
      DOTC(a6, sXd4[6], acc) DOTC(a7, sXd4[7], acc) DOTC(a8, sXd4[8], acc)
      DOTC(a9, sXd4[9], acc)
#pragma unroll
      for (int k = 0; k < 4; ++k) {
        int4 w = lWg4[k * 600 + j];
        DOTC(w, sXd4[10 + k], acc)
      }
      {
        const int4* sp = WgS4 + j;
        int4 f0 = sp[0], f1 = sp[600];
#pragma unroll
        for (int k = 0; k < 24; ++k) {
          int4 w = f0;
          f0 = f1;
          if (k < 22) f1 = sp[(k + 2) * 600];
          DOTC(w, sXd4[14 + k], acc)
        }
      }
      float rb;
      if (j < 150)
        rb = sU[j];
      else if (j < 300)
        rb = sU[j - 150];
      else if (j < 450)
        rb = sC0[j - 300];
      else
        rb = sC0[j - 450];
      float rg = rb * fast_sigmoid(acc);
      int idx = (j < 300) ? j : (j + 4);
      ((__half*)sRgh)[idx] = __float2half(rg);
    }
    __syncthreads();

    // ---- Phase E: gi = W_ih * rg + b_ih (half-rows, pair-reduce)
    if (t < 900) {
      const int hf = t & 1, r = t >> 1;
      const int4* x4 = ((const int4*)sRgh) + hf * 38;
      float acc = 0.f;
      DOTC(b0, x4[0], acc) DOTC(b1, x4[1], acc) DOTC(b2, x4[2], acc)
      DOTC(b3, x4[3], acc) DOTC(b4, x4[4], acc) DOTC(b5, x4[5], acc)
      DOTC(b6, x4[6], acc) DOTC(b7, x4[7], acc) DOTC(b8, x4[8], acc)
      DOTC(b9, x4[9], acc)
      {
        int4 w = lWih4[t];
        DOTC(w, x4[10], acc)
        w = lWih4[900 + t];
        DOTC(w, x4[11], acc)
      }
      {
        const int4* sp = WihS4 + t;
        int4 f0 = sp[0], f1 = sp[900];
#pragma unroll
        for (int k = 0; k < 26; ++k) {
          int4 w = f0;
          f0 = f1;
          if (k < 24) f1 = sp[(k + 2) * 900];
          DOTC(w, x4[12 + k], acc)
        }
      }
      float other = __shfl_xor(acc, 1);
      if (!hf) sGi[r] = acc + other + sBih[r];
    }
    __syncthreads();

    // ---- Phase F: GRU update + output store; loaders stage next u
    if (t < 150) {
      float ir = sGi[t], iz = sGi[150 + t], in_ = sGi[300 + t];
      float hr = sGh[t], hz = sGh[150 + t], hn = sGh[300 + t];
      float rr = fast_sigmoid(ir + hr);
      float zz = fast_sigmoid(iz + hz);
      float nn = fast_tanh(in_ + rr * hn);
      float vold = sv_[t];
      float hv = nn + zz * (vold - nn);
      out[i * 9600 + b * 150 + t] = hv;
      sv_[t] = hv;
      float hv1 = __shfl_down(hv, 1);
      if (!(t & 1)) svh[t >> 1] = packh2(hv, hv1);
    } else if (t >= 256 && t < 406) {
      int t2 = t - 256;
      sU[t2] = unext;
      float un = __shfl_down(unext, 1);
      if (!(t2 & 1)) sXd[t2 >> 1] = packh2(unext, un);
    }
    __syncthreads();
  }
}

// ---------------------------------------------------------------------------
extern "C" void kernel_launch(void* const* d_in, const int* in_sizes, int n_in,
                              void* d_out, int out_size, void* d_ws,
                              size_t ws_size, hipStream_t stream) {
  const float* Up = (const float*)d_in[0];
  const float* Uq = (const float*)d_in[1];
  const float* Wp = (const float*)d_in[2];
  const float* Wq = (const float*)d_in[3];
  const float* Wv = (const float*)d_in[4];
  const float* Wg = (const float*)d_in[5];
  const float* V = (const float*)d_in[6];
  const float* v0 = (const float*)d_in[7];
  const float* Wih = (const float*)d_in[8];
  const float* Whh = (const float*)d_in[9];
  const float* bih = (const float*)d_in[10];
  const float* bhh = (const float*)d_in[11];

  char* ws = (char*)d_ws;
  __half* wsWuq = (__half*)(ws);                 // 2,490,368 B
  __half* wsUqh = (__half*)(ws + 2490368);       // 2,490,368 B
  __half* wsMa = (__half*)(ws + 4980736);        //    91,200 B
  __half* wsWg = (__half*)(ws + 5071936);        //   364,800 B
  __half* wsWih = (__half*)(ws + 5436736);       //   547,200 B
  __half* wsWhh = (__half*)(ws + 5983936);       //   137,408 B

  static bool attr_done = false;
  (void)hipFuncSetAttribute((const void*)pq_main,
                            hipFuncAttributeMaxDynamicSharedMemorySize, 98464);
  (void)attr_done;

  prep_weights<<<2228, 256, 0, stream>>>(Wp, Wv, Wg, Wih, Whh, wsMa, wsWg,
                                         wsWih, wsWhh);
  prep_wuq<<<128, 256, 0, stream>>>(Uq, Wq, wsWuq, wsUqh);
  pq_main<<<64, 1024, 98464, stream>>>(Up, V, v0, bih, bhh, (const int*)wsWuq,
                                       wsUqh, (const int*)wsMa, (const int*)wsWg,
                                       (const int*)wsWih, (const int*)wsWhh,
                                       (float*)d_out);
}